// Round 1
// baseline (192.029 us; speedup 1.0000x reference)
//
#include <hip/hip_runtime.h>

#define BATCH 32
#define NCAPS 32
#define NR    4608
#define NI    8
#define NO    16
#define CSTR  200   // LDS floats per capsule: 16 o * 12 (8 used + 4 pad) = 192, pad to 200 (bank decorrelation)

// Routing pass: for each route node r, compute u[c] = x[b,r,:] . W[c,r,:,o],
// softmax over c of (u[c]*A[b,c,o]), accumulate sum_r C*u into per-chunk partials.
__global__ __launch_bounds__(512, 2) void caps_route_pass(
    const float* __restrict__ x,    // [B][R][I]
    const float* __restrict__ W,    // [C][R][I][O]
    const float* __restrict__ A,    // [B][C][O]  (routing state, = sum of V's)
    float* __restrict__ P,          // [nchunk][B][C][O] partial S
    int rb)
{
    __shared__ float Ws[NCAPS * CSTR];   // 25.6 KB

    const int tid = threadIdx.x;   // 512 threads = 32 b * 16 o
    const int b = tid >> 4;
    const int o = tid & 15;
    const int r0 = blockIdx.x * rb;

    // Per-thread routing coefficients A[b, :, o] (constant over r) -> 32 regs
    float a[NCAPS];
#pragma unroll
    for (int c = 0; c < NCAPS; ++c) a[c] = A[(b * NCAPS + c) * NO + o];

    float acc[NCAPS];
#pragma unroll
    for (int c = 0; c < NCAPS; ++c) acc[c] = 0.f;

    // Staging role: thread stages 8 contiguous floats of W[cs, r, :, :]
    const int cs  = tid >> 4;          // capsule to stage (0..31)
    const int seg = tid & 15;          // which 8-float segment of the 128-float (i,o) block
    const int iw  = seg >> 1;          // i index of the segment
    const int ob  = (seg & 1) * 8;     // o base of the segment
    const float* wsrc = W + ((size_t)cs * NR + r0) * (NI * NO) + seg * 8;
    const float* xp   = x + ((size_t)b * NR + r0) * NI;

    // register prefetch (double-buffer: global -> reg while computing, reg -> LDS at sync)
    float4 pf0 = *(const float4*)(wsrc);
    float4 pf1 = *(const float4*)(wsrc + 4);

    for (int rr = 0; rr < rb; ++rr) {
        __syncthreads();   // previous iteration's readers done
        {
            const float tmp[8] = {pf0.x, pf0.y, pf0.z, pf0.w, pf1.x, pf1.y, pf1.z, pf1.w};
#pragma unroll
            for (int k = 0; k < 8; ++k)
                Ws[cs * CSTR + (ob + k) * 12 + iw] = tmp[k];
        }
        if (rr + 1 < rb) {
            wsrc += NI * NO;
            pf0 = *(const float4*)(wsrc);
            pf1 = *(const float4*)(wsrc + 4);
        }
        __syncthreads();

        const float4 xv0 = *(const float4*)(xp);
        const float4 xv1 = *(const float4*)(xp + 4);
        xp += NI;

        float u[NCAPS], e[NCAPS];
        float m = -3.0e38f;
#pragma unroll
        for (int c = 0; c < NCAPS; ++c) {
            const float* wp = &Ws[c * CSTR + o * 12];
            const float4 w0 = *(const float4*)(wp);
            const float4 w1 = *(const float4*)(wp + 4);
            float uu =      xv0.x * w0.x;
            uu = fmaf(xv0.y, w0.y, uu);
            uu = fmaf(xv0.z, w0.z, uu);
            uu = fmaf(xv0.w, w0.w, uu);
            uu = fmaf(xv1.x, w1.x, uu);
            uu = fmaf(xv1.y, w1.y, uu);
            uu = fmaf(xv1.z, w1.z, uu);
            uu = fmaf(xv1.w, w1.w, uu);
            u[c] = uu;
            const float l = uu * a[c];   // logit = U * A  (== B)
            e[c] = l;
            m = fmaxf(m, l);
        }
        float Z = 0.f;
#pragma unroll
        for (int c = 0; c < NCAPS; ++c) {
            const float ee = __expf(e[c] - m);
            e[c] = ee;
            Z += ee;
        }
        const float rz = 1.0f / Z;
#pragma unroll
        for (int c = 0; c < NCAPS; ++c)
            acc[c] = fmaf(e[c] * rz, u[c], acc[c]);   // S += softmax_c * u
    }

    float* pout = P + (((size_t)blockIdx.x * BATCH + b) * NCAPS) * NO + o;
#pragma unroll
    for (int c = 0; c < NCAPS; ++c) pout[c * NO] = acc[c];
}

// Reduce partials over chunks, squash, update A; optionally emit V (final iter).
__global__ void caps_reduce_squash(const float* __restrict__ P,
                                   float* __restrict__ A,
                                   float* __restrict__ out,
                                   int nchunk)
{
    __shared__ float sm[256];
    const int bc  = blockIdx.x;     // b*NCAPS + c  (1024 blocks)
    const int tid = threadIdx.x;    // 256 = 16 j * 16 o
    const int o = tid & 15;
    const int j = tid >> 4;
    float s = 0.f;
    for (int t = j; t < nchunk; t += 16)
        s += P[((size_t)t * (BATCH * NCAPS) + bc) * NO + o];
    sm[tid] = s;
    __syncthreads();
    if (tid < 16) {
        float S = 0.f;
#pragma unroll
        for (int k = 0; k < 16; ++k) S += sm[tid + 16 * k];
        float sq = S * S;
#pragma unroll
        for (int d = 8; d >= 1; d >>= 1) sq += __shfl_xor(sq, d, 16);
        const float scale = sq / ((1.f + sq) * sqrtf(sq));   // sn/((1+sn)*sqrt(sn))
        const float V = S * scale;
        const int idx = bc * NO + tid;
        A[idx] += V;
        if (out) out[idx] = V;
    }
}

__global__ void caps_zero(float* __restrict__ p, int n)
{
    const int i = blockIdx.x * blockDim.x + threadIdx.x;
    if (i < n) p[i] = 0.f;
}

extern "C" void kernel_launch(void* const* d_in, const int* in_sizes, int n_in,
                              void* d_out, int out_size, void* d_ws, size_t ws_size,
                              hipStream_t stream)
{
    const float* x = (const float*)d_in[0];   // [32][4608][8]
    const float* W = (const float*)d_in[1];   // [32][4608][8][16]
    float* out = (float*)d_out;               // [32][32][16]

    float* A = (float*)d_ws;                        // 16384 floats
    float* P = A + BATCH * NCAPS * NO;              // nchunk * 16384 floats

    // Pick largest power-of-two chunk count whose partial buffer fits the workspace.
    int nchunk = 256;
    while (nchunk > 1 &&
           (size_t)(nchunk + 1) * (BATCH * NCAPS * NO) * sizeof(float) > ws_size)
        nchunk >>= 1;
    const int rb = NR / nchunk;   // 4608 is divisible by all powers of two up to 512

    caps_zero<<<(BATCH * NCAPS * NO + 255) / 256, 256, 0, stream>>>(A, BATCH * NCAPS * NO);

    for (int it = 0; it < 3; ++it) {
        caps_route_pass<<<nchunk, 512, 0, stream>>>(x, W, A, P, rb);
        caps_reduce_squash<<<BATCH * NCAPS, 256, 0, stream>>>(
            P, A, it == 2 ? out : nullptr, nchunk);
    }
}